// Round 3
// baseline (323.985 us; speedup 1.0000x reference)
//
#include <hip/hip_runtime.h>

// LSTMModel: B=4096, T=512, IN=2, H=12, OUT=2, fp32.
// Decomposition: ONE batch element per wave64; lane = (unit u = lane>>2, gate = lane&3).
//   48 active lanes (12 units x 4 gates), rows r = gate*12 + u of the 48x* weight mats.
// 1024 blocks x 256 threads = 4096 waves = 4 waves/SIMD (latency hiding).
// h is wave-uniform -> broadcast via v_readlane into SGPRs (FMA scalar operand).
// Gate gather (i,f,g,o of one unit live in one quad) via DPP quad_perm (pure VALU).
// Zero LDS / DS instructions in the loop.

namespace {
constexpr int H  = 12;
constexpr int T  = 512;
constexpr int IN = 2;
constexpr float LOG2E = 1.4426950408889634f;

__device__ __forceinline__ float exp2_(float x) {
    float r;
    asm("v_exp_f32 %0, %1" : "=v"(r) : "v"(x));
    return r;
}
__device__ __forceinline__ float rcp_(float x) { return __builtin_amdgcn_rcpf(x); }

// quad_perm rotations: lane 4u reads 4u+1 / 4u+2 / 4u+3
template <int CTRL>
__device__ __forceinline__ float dppf(float v) {
    return __int_as_float(__builtin_amdgcn_update_dpp(
        __float_as_int(v), __float_as_int(v), CTRL, 0xF, 0xF, true));
}
constexpr int QP1 = 0x39;  // [1,2,3,0]
constexpr int QP2 = 0x4E;  // [2,3,0,1]
constexpr int QP3 = 0x93;  // [3,0,1,2]

__device__ __forceinline__ float rdl(float v, int l) {
    return __int_as_float(__builtin_amdgcn_readlane(__float_as_int(v), l));
}
// tanh(c) = 2/(1+2^(-2*log2e*c)) - 1
__device__ __forceinline__ float tanh_(float c) {
    return fmaf(2.0f, rcp_(1.0f + exp2_(-2.0f * LOG2E * c)), -1.0f);
}
} // namespace

__global__ __launch_bounds__(256, 4) void lstm2_fc_kernel(
    const float* __restrict__ x,      // (4096, 512, 2)
    const float* __restrict__ W_ih0,  // (48, 2)
    const float* __restrict__ W_hh0,  // (48, 12)
    const float* __restrict__ b_ih0,  // (48)
    const float* __restrict__ b_hh0,  // (48)
    const float* __restrict__ W_ih1,  // (48, 12)
    const float* __restrict__ W_hh1,  // (48, 12)
    const float* __restrict__ b_ih1,  // (48)
    const float* __restrict__ b_hh1,  // (48)
    const float* __restrict__ fc_W,   // (2, 12)
    const float* __restrict__ fc_b,   // (2)
    float* __restrict__ out)          // (4096, 2)
{
    const int lane = threadIdx.x & 63;
    const int wid  = __builtin_amdgcn_readfirstlane((int)threadIdx.x >> 6);
    const int b    = blockIdx.x * 4 + wid;       // one element per wave
    const int u    = lane >> 2;                  // unit 0..15 (12 active)
    const int gate = lane & 3;                   // 0:i 1:f 2:g 3:o
    const int uc   = (u < H) ? u : 0;            // clamp idle lanes
    const int r    = gate * H + uc;              // weight row

    // activation shaping: sigmoid for i,f,o; tanh (=2*sigm(2x)-1) for g
    const float pre  = (gate == 2) ? 2.0f : 1.0f;
    const float kmul = -LOG2E * pre;             // exp2 premultiplier
    const float pa   = 1.0f - pre;

    // ---------------- weights -> registers (38 floats/lane) ----------------
    const float wx0 = W_ih0[r * IN + 0];
    const float wx1 = W_ih0[r * IN + 1];
    float whh0[H], wih1[H], whh1[H];
#pragma unroll
    for (int j = 0; j < H; ++j) {
        whh0[j] = W_hh0[r * H + j];
        wih1[j] = W_ih1[r * H + j];
        whh1[j] = W_hh1[r * H + j];
    }
    const float bias0 = b_ih0[r] + b_hh0[r];
    const float bias1 = b_ih1[r] + b_hh1[r];

    // ---------------- state: h wave-uniform (SGPRs), c per-lane ----------------
    float c0 = 0.0f, c1 = 0.0f;
    float h0s[H], h1s[H];
#pragma unroll
    for (int j = 0; j < H; ++j) { h0s[j] = 0.0f; h1s[j] = 0.0f; }

    const float* xp = x + (size_t)b * T * IN;    // wave-uniform pointer
    float xv0 = xp[0], xv1 = xp[1];

    for (int t = 0; t < T; ++t) {
        const int tn = (t < T - 1) ? (t + 1) : t;
        const float xn0 = xp[2 * tn + 0];
        const float xn1 = xp[2 * tn + 1];

        // ---- layer 0: row dot (two chains for ILP) ----
        float aA = fmaf(wx0, xv0, bias0);
        aA = fmaf(wx1, xv1, aA);
        float aB = whh0[0] * h0s[0];
#pragma unroll
        for (int j = 1; j < 6; ++j) aB = fmaf(whh0[j], h0s[j], aB);
#pragma unroll
        for (int j = 6; j < H; ++j) aA = fmaf(whh0[j], h0s[j], aA);
        const float a0 = aA + aB;

        const float s0 = fmaf(pre, rcp_(1.0f + exp2_(kmul * a0)), pa);
        const float f0 = dppf<QP1>(s0);          // lane 4u <- f
        const float g0 = dppf<QP2>(s0);          // lane 4u <- g
        const float o0 = dppf<QP3>(s0);          // lane 4u <- o
        c0 = fmaf(f0, c0, s0 * g0);              // valid on gate-0 lanes
        const float h0v = o0 * tanh_(c0);
#pragma unroll
        for (int j = 0; j < H; ++j) h0s[j] = rdl(h0v, 4 * j);

        // ---- layer 1: whh1.h1(t-1) chains first (independent of h0s(t)) ----
        float bA = bias1;
#pragma unroll
        for (int j = 0; j < 6; ++j) bA = fmaf(whh1[j], h1s[j], bA);
        float bB = whh1[6] * h1s[6];
#pragma unroll
        for (int j = 7; j < H; ++j) bB = fmaf(whh1[j], h1s[j], bB);
#pragma unroll
        for (int j = 0; j < 6; ++j) bA = fmaf(wih1[j], h0s[j], bA);
#pragma unroll
        for (int j = 6; j < H; ++j) bB = fmaf(wih1[j], h0s[j], bB);
        const float a1 = bA + bB;

        const float s1 = fmaf(pre, rcp_(1.0f + exp2_(kmul * a1)), pa);
        const float f1 = dppf<QP1>(s1);
        const float g1 = dppf<QP2>(s1);
        const float o1 = dppf<QP3>(s1);
        c1 = fmaf(f1, c1, s1 * g1);
        const float h1v = o1 * tanh_(c1);
#pragma unroll
        for (int j = 0; j < H; ++j) h1s[j] = rdl(h1v, 4 * j);

        xv0 = xn0; xv1 = xn1;
    }

    // ---------------- final FC (once, lane 0) ----------------
    if (lane == 0) {
        float r0 = fc_b[0];
        float r1 = fc_b[1];
#pragma unroll
        for (int j = 0; j < H; ++j) {
            r0 = fmaf(fc_W[j],     h1s[j], r0);
            r1 = fmaf(fc_W[H + j], h1s[j], r1);
        }
        float2 res; res.x = r0; res.y = r1;
        *(float2*)(out + (size_t)b * 2) = res;
    }
}

extern "C" void kernel_launch(void* const* d_in, const int* in_sizes, int n_in,
                              void* d_out, int out_size, void* d_ws, size_t ws_size,
                              hipStream_t stream) {
    const float* x     = (const float*)d_in[0];
    const float* W_ih0 = (const float*)d_in[1];
    const float* W_hh0 = (const float*)d_in[2];
    const float* b_ih0 = (const float*)d_in[3];
    const float* b_hh0 = (const float*)d_in[4];
    const float* W_ih1 = (const float*)d_in[5];
    const float* W_hh1 = (const float*)d_in[6];
    const float* b_ih1 = (const float*)d_in[7];
    const float* b_hh1 = (const float*)d_in[8];
    const float* fc_W  = (const float*)d_in[9];
    const float* fc_b  = (const float*)d_in[10];
    float* out = (float*)d_out;

    // 4096 elements, 1 per wave, 4 waves per block -> 1024 blocks
    lstm2_fc_kernel<<<1024, 256, 0, stream>>>(
        x, W_ih0, W_hh0, b_ih0, b_hh0,
        W_ih1, W_hh1, b_ih1, b_hh1, fc_W, fc_b, out);
}

// Round 4
// 257.996 us; speedup vs baseline: 1.2558x; 1.2558x over previous
//
#include <hip/hip_runtime.h>

// LSTMModel: B=4096, T=512, IN=2, H=12, OUT=2, fp32.
// One batch element per wave64; lane = (unit u = lane>>2, gate = lane&3).
// 1024 blocks x 256 threads -> 4096 waves = 4 waves/SIMD.
// v_pk_fma_f32 packs the gate dot products (2 MACs/instr).
// h broadcast through per-wave private LDS: 1 ds_write_b32 + 6 ds_read_b64
// per layer (DS pipe, off the VALU issue port). No barriers needed.
// Gate gather (i,f,g,o within a quad) via DPP quad_perm.

namespace {
constexpr int H  = 12;
constexpr int T  = 512;
constexpr int IN = 2;
constexpr float LOG2E = 1.4426950408889634f;

typedef float f2 __attribute__((ext_vector_type(2)));

__device__ __forceinline__ f2 pk_fma(f2 a, f2 b, f2 c) {
    f2 d;
    asm("v_pk_fma_f32 %0, %1, %2, %3" : "=v"(d) : "v"(a), "v"(b), "v"(c));
    return d;
}
__device__ __forceinline__ float exp2_(float x) {
    float r;
    asm("v_exp_f32 %0, %1" : "=v"(r) : "v"(x));
    return r;
}
__device__ __forceinline__ float rcp_(float x) { return __builtin_amdgcn_rcpf(x); }

template <int CTRL>
__device__ __forceinline__ float dppf(float v) {
    return __int_as_float(__builtin_amdgcn_update_dpp(
        __float_as_int(v), __float_as_int(v), CTRL, 0xF, 0xF, true));
}
constexpr int QP1 = 0x39;  // quad_perm [1,2,3,0]
constexpr int QP2 = 0x4E;  // quad_perm [2,3,0,1]
constexpr int QP3 = 0x93;  // quad_perm [3,0,1,2]

// tanh(c) = 2/(1+2^(-2*log2e*c)) - 1
__device__ __forceinline__ float tanh_(float c) {
    return fmaf(2.0f, rcp_(1.0f + exp2_(-2.0f * LOG2E * c)), -1.0f);
}
} // namespace

__global__ __launch_bounds__(256, 4) void lstm2_fc_kernel(
    const float* __restrict__ x,      // (4096, 512, 2)
    const float* __restrict__ W_ih0,  // (48, 2)
    const float* __restrict__ W_hh0,  // (48, 12)
    const float* __restrict__ b_ih0,  // (48)
    const float* __restrict__ b_hh0,  // (48)
    const float* __restrict__ W_ih1,  // (48, 12)
    const float* __restrict__ W_hh1,  // (48, 12)
    const float* __restrict__ b_ih1,  // (48)
    const float* __restrict__ b_hh1,  // (48)
    const float* __restrict__ fc_W,   // (2, 12)
    const float* __restrict__ fc_b,   // (2)
    float* __restrict__ out)          // (4096, 2)
{
    const int lane = threadIdx.x & 63;
    const int wid  = __builtin_amdgcn_readfirstlane((int)threadIdx.x >> 6);
    const int b    = blockIdx.x * 4 + wid;       // one element per wave
    const int u    = lane >> 2;                  // unit 0..15 (12 active)
    const int gate = lane & 3;                   // 0:i 1:f 2:g 3:o
    const int uc   = (u < H) ? u : 0;            // clamp idle lanes
    const int r    = gate * H + uc;              // weight row

    // sigmoid for i,f,o; tanh (=2*sigm(2x)-1) for g. Fold the exp2 scaling
    // kmul = -log2e*pre into weights & bias so the dot product feeds exp2
    // directly.
    const float pre  = (gate == 2) ? 2.0f : 1.0f;
    const float kmul = -LOG2E * pre;
    const float pa   = 1.0f - pre;

    // ---- per-wave private LDS: compact h (12 floats) + dump per layer ----
    __shared__ __align__(16) float sm[4 * 2 * 96];
    const int base0 = wid * 192;                 // layer-0 h region (floats)
    const int base1 = base0 + 96;                // layer-1 h region
    // gate-0 lanes of active units write compact slot u; all others dump
    const bool writer = (gate == 0) && (u < H);
    const int  woff   = writer ? uc : (16 + lane);
    const int  wslot0 = base0 + woff;
    const int  wslot1 = base1 + woff;

    // ---------------- prescaled weights -> registers ----------------
    f2 wx, whh0p[6], wih1p[6], whh1p[6];
    wx.x = kmul * W_ih0[r * IN + 0];
    wx.y = kmul * W_ih0[r * IN + 1];
#pragma unroll
    for (int k = 0; k < 6; ++k) {
        whh0p[k].x = kmul * W_hh0[r * H + 2 * k];
        whh0p[k].y = kmul * W_hh0[r * H + 2 * k + 1];
        wih1p[k].x = kmul * W_ih1[r * H + 2 * k];
        wih1p[k].y = kmul * W_ih1[r * H + 2 * k + 1];
        whh1p[k].x = kmul * W_hh1[r * H + 2 * k];
        whh1p[k].y = kmul * W_hh1[r * H + 2 * k + 1];
    }
    f2 bias0p, bias1p;
    bias0p.x = kmul * (b_ih0[r] + b_hh0[r]); bias0p.y = 0.0f;
    bias1p.x = kmul * (b_ih1[r] + b_hh1[r]); bias1p.y = 0.0f;

    // ---------------- state ----------------
    float c0 = 0.0f, c1 = 0.0f;
    f2 hp0[6], hq1[6];
#pragma unroll
    for (int k = 0; k < 6; ++k) { hp0[k] = (f2)(0.0f); hq1[k] = (f2)(0.0f); }

    const float* xp = x + (size_t)b * T * IN;
    f2 xv; xv.x = xp[0]; xv.y = xp[1];

    for (int t = 0; t < T; ++t) {
        const int tn = (t < T - 1) ? (t + 1) : t;
        f2 xn; xn.x = xp[2 * tn + 0]; xn.y = xp[2 * tn + 1];

        // ---- layer 0: packed row dot (result already scaled by kmul) ----
        f2 acc = pk_fma(wx, xv, bias0p);
#pragma unroll
        for (int k = 0; k < 6; ++k) acc = pk_fma(whh0p[k], hp0[k], acc);
        const float s0 = fmaf(pre, rcp_(1.0f + exp2_(acc.x + acc.y)), pa);
        const float f0 = dppf<QP1>(s0);
        const float g0 = dppf<QP2>(s0);
        const float o0 = dppf<QP3>(s0);
        c0 = fmaf(f0, c0, s0 * g0);              // valid on gate-0 lanes
        const float h0v = o0 * tanh_(c0);
        sm[wslot0] = h0v;                        // publish h0(t)

        // ---- layer 1: whh1 . h1(t-1) first (covers the LDS round-trip) ----
        f2 accC = pk_fma(whh1p[0], hq1[0], bias1p);
#pragma unroll
        for (int k = 1; k < 6; ++k) accC = pk_fma(whh1p[k], hq1[k], accC);
        // read back h0(t) pairs (reused next step for whh0 dot)
#pragma unroll
        for (int k = 0; k < 6; ++k) hp0[k] = *(const f2*)&sm[base0 + 2 * k];
#pragma unroll
        for (int k = 0; k < 6; ++k) accC = pk_fma(wih1p[k], hp0[k], accC);
        const float s1 = fmaf(pre, rcp_(1.0f + exp2_(accC.x + accC.y)), pa);
        const float f1 = dppf<QP1>(s1);
        const float g1 = dppf<QP2>(s1);
        const float o1 = dppf<QP3>(s1);
        c1 = fmaf(f1, c1, s1 * g1);
        const float h1v = o1 * tanh_(c1);
        sm[wslot1] = h1v;                        // publish h1(t)
#pragma unroll
        for (int k = 0; k < 6; ++k) hq1[k] = *(const f2*)&sm[base1 + 2 * k];

        xv = xn;
    }

    // ---------------- final FC (lane 0; hq1 holds h1(T-1) pairs) ----------------
    if (lane == 0) {
        float r0 = fc_b[0];
        float r1 = fc_b[1];
#pragma unroll
        for (int k = 0; k < 6; ++k) {
            r0 = fmaf(fc_W[2 * k], hq1[k].x, r0);
            r0 = fmaf(fc_W[2 * k + 1], hq1[k].y, r0);
            r1 = fmaf(fc_W[H + 2 * k], hq1[k].x, r1);
            r1 = fmaf(fc_W[H + 2 * k + 1], hq1[k].y, r1);
        }
        float2 res; res.x = r0; res.y = r1;
        *(float2*)(out + (size_t)b * 2) = res;
    }
}

extern "C" void kernel_launch(void* const* d_in, const int* in_sizes, int n_in,
                              void* d_out, int out_size, void* d_ws, size_t ws_size,
                              hipStream_t stream) {
    const float* x     = (const float*)d_in[0];
    const float* W_ih0 = (const float*)d_in[1];
    const float* W_hh0 = (const float*)d_in[2];
    const float* b_ih0 = (const float*)d_in[3];
    const float* b_hh0 = (const float*)d_in[4];
    const float* W_ih1 = (const float*)d_in[5];
    const float* W_hh1 = (const float*)d_in[6];
    const float* b_ih1 = (const float*)d_in[7];
    const float* b_hh1 = (const float*)d_in[8];
    const float* fc_W  = (const float*)d_in[9];
    const float* fc_b  = (const float*)d_in[10];
    float* out = (float*)d_out;

    // 4096 elements, 1 per wave, 4 waves per block -> 1024 blocks
    lstm2_fc_kernel<<<1024, 256, 0, stream>>>(
        x, W_ih0, W_hh0, b_ih0, b_hh0,
        W_ih1, W_hh1, b_ih1, b_hh1, fc_W, fc_b, out);
}